// Round 7
// baseline (2160.885 us; speedup 1.0000x reference)
//
#include <hip/hip_runtime.h>
#include <math.h>

// LSTM: I=5, H=64, L=3, O=1, B=1024, T=256, fp32.
// Round-7: fit the 128-VGPR cap by construction. r5/r6 evidence: allocator
// refuses >128 VGPRs (attributes ignored), so the 128-float weight set
// spilled (46+59 MB HBM). Now 8-way k-split: 512 threads, thread
// (u=tid>>3, s=tid&7) owns all 4 gate rows of unit u over k-octet
// [8s,8s+8): weights = 4 gates x 2 float4 x 2 matrices = 16 float4 = 64
// VGPR; total ~115 < 128. Octet reduction: 2 fused DPP quad-adds +
// ds_swizzle xor-4. Still ONE barrier/step, 16 FMA per ds_read_b128,
// chunk buffers double as recurrent state (read [tt-1], write [tt]).
// LDS reads: same-s lanes broadcast; s vs s+4 2-way conflict = free (m136).

constexpr int Hh = 64;
constexpr int Tt = 256;   // timesteps
constexpr int In = 5;     // input size
constexpr int TB = 2;     // batch elems per block
constexpr int TC = 64;    // timestep chunk
constexpr int NB = 512;   // blocks (NB*TB = 1024 = B)
constexpr int NT = 512;   // threads per block

__device__ __forceinline__ float sigm(float x) { return 1.0f / (1.0f + __expf(-x)); }
__device__ __forceinline__ float tanh_fast(float x) {
    float ax = fabsf(x);
    float t = __expf(-2.0f * ax);      // in (0,1], no overflow
    float r = (1.0f - t) / (1.0f + t);
    return copysignf(r, x);
}

// quad_perm DPP
template<int CTRL>
__device__ __forceinline__ float qp(float v) {
    int r = __builtin_amdgcn_update_dpp(0, __builtin_bit_cast(int, v),
                                        CTRL, 0xF, 0xF, true);
    return __builtin_bit_cast(float, r);
}
// sum across the 8 lanes of each octet (s = lane&7)
__device__ __forceinline__ float octet_sum(float a) {
    a += qp<0xB1>(a);   // xor 1
    a += qp<0x4E>(a);   // xor 2
    int t = __builtin_amdgcn_ds_swizzle(__builtin_bit_cast(int, a), 0x101F); // xor 4
    a += __builtin_bit_cast(float, t);
    return a;
}

#define DOT4(W, H) ((W).x*(H).x + (W).y*(H).y + (W).z*(H).z + (W).w*(H).w)

__global__ __launch_bounds__(NT, 2) void lstm3_fused(
    const float* __restrict__ x,
    const float* __restrict__ w_ih0, const float* __restrict__ w_hh0,
    const float* __restrict__ b_ih0, const float* __restrict__ b_hh0,
    const float* __restrict__ w_ih1, const float* __restrict__ w_hh1,
    const float* __restrict__ b_ih1, const float* __restrict__ b_hh1,
    const float* __restrict__ w_ih2, const float* __restrict__ w_hh2,
    const float* __restrict__ b_ih2, const float* __restrict__ b_hh2,
    const float* __restrict__ w_fc,  const float* __restrict__ b_fc,
    float* __restrict__ out, int nch)
{
    __shared__ alignas(16) float buf0[TB][TC][Hh];   // layer0 h chunk (32 KB)
    __shared__ alignas(16) float buf1[TB][TC][Hh];   // layer1 h chunk (32 KB)
    __shared__ alignas(16) float h2b[2][TB][Hh];     // layer2 rolling h (1 KB)
    __shared__ alignas(16) float xs[TB][TC][8];      // staged input chunk (4 KB)

    const int tid = threadIdx.x;
    const int u   = tid >> 3;        // hidden unit 0..63
    const int s   = tid & 7;         // k-octet
    const int ko  = 8 * s;           // k offset (floats)
    const int b0  = blockIdx.x * TB;

    // c-state in registers, replicated across the 8 lanes of each octet
    float c00 = 0.f, c01 = 0.f;   // layer0: batch 0,1
    float c10 = 0.f, c11 = 0.f;   // layer1
    float c20 = 0.f, c21 = 0.f;   // layer2

    for (int i = tid; i < TB * TC * Hh; i += NT) { ((float*)buf0)[i] = 0.f; ((float*)buf1)[i] = 0.f; }
    for (int i = tid; i < 2 * TB * Hh; i += NT) ((float*)h2b)[i] = 0.f;

    #pragma unroll 1
    for (int chunk = 0; chunk < nch; ++chunk) {
        const int t0 = chunk * TC;

        // ---- stage x chunk: xs[b][t][0..4], pad 5..7 ----
        for (int i = tid; i < TB * TC * 8; i += NT) {
            int b  = i >> 9;
            int r  = i & 511;
            int t  = r >> 3;
            int cc = r & 7;
            xs[b][t][cc] = (cc < In)
                ? x[((size_t)(b0 + b) * Tt + (t0 + t)) * In + cc] : 0.f;
        }

        // ================= layer 0 =================
        {
            asm volatile("" ::: "memory");   // keep weight loads inside the chunk loop
            const float4* p0 = reinterpret_cast<const float4*>(w_hh0 + (size_t)(0*Hh+u)*Hh + ko);
            const float4* p1 = reinterpret_cast<const float4*>(w_hh0 + (size_t)(1*Hh+u)*Hh + ko);
            const float4* p2 = reinterpret_cast<const float4*>(w_hh0 + (size_t)(2*Hh+u)*Hh + ko);
            const float4* p3 = reinterpret_cast<const float4*>(w_hh0 + (size_t)(3*Hh+u)*Hh + ko);
            float4 whA0=p0[0], whB0=p0[1];
            float4 whA1=p1[0], whB1=p1[1];
            float4 whA2=p2[0], whB2=p2[1];
            float4 whA3=p3[0], whB3=p3[1];
            // input weights (5 wide): s==0 lanes only, zeros elsewhere
            float4 wx0={0,0,0,0}, wx1={0,0,0,0}, wx2={0,0,0,0}, wx3={0,0,0,0};
            float wq0=0.f, wq1=0.f, wq2=0.f, wq3=0.f;
            if (s == 0) {
                const float* q0 = w_ih0 + (0*Hh+u)*In;
                const float* q1 = w_ih0 + (1*Hh+u)*In;
                const float* q2 = w_ih0 + (2*Hh+u)*In;
                const float* q3 = w_ih0 + (3*Hh+u)*In;
                wx0 = make_float4(q0[0],q0[1],q0[2],q0[3]); wq0 = q0[4];
                wx1 = make_float4(q1[0],q1[1],q1[2],q1[3]); wq1 = q1[4];
                wx2 = make_float4(q2[0],q2[1],q2[2],q2[3]); wq2 = q2[4];
                wx3 = make_float4(q3[0],q3[1],q3[2],q3[3]); wq3 = q3[4];
            }
            const float bi0 = b_ih0[0*Hh+u] + b_hh0[0*Hh+u];
            const float bi1 = b_ih0[1*Hh+u] + b_hh0[1*Hh+u];
            const float bi2 = b_ih0[2*Hh+u] + b_hh0[2*Hh+u];
            const float bi3 = b_ih0[3*Hh+u] + b_hh0[3*Hh+u];
            __syncthreads();   // xs staged; buffers zeroed (chunk 0)

            #pragma unroll 1
            for (int tt = 0; tt < TC; ++tt) {
                const int tp = (tt == 0) ? (TC - 1) : (tt - 1);
                float a00,a10,a20,a30, a01,a11,a21,a31;
                {
                    const float4* hp = reinterpret_cast<const float4*>(&buf0[0][tp][ko]);
                    float4 hA = hp[0], hB = hp[1];
                    float4 xv = *reinterpret_cast<const float4*>(&xs[0][tt][0]);
                    float  xq = xs[0][tt][4];
                    a00 = DOT4(whA0,hA)+DOT4(whB0,hB) + DOT4(wx0,xv)+wq0*xq;
                    a10 = DOT4(whA1,hA)+DOT4(whB1,hB) + DOT4(wx1,xv)+wq1*xq;
                    a20 = DOT4(whA2,hA)+DOT4(whB2,hB) + DOT4(wx2,xv)+wq2*xq;
                    a30 = DOT4(whA3,hA)+DOT4(whB3,hB) + DOT4(wx3,xv)+wq3*xq;
                }
                {
                    const float4* hp = reinterpret_cast<const float4*>(&buf0[1][tp][ko]);
                    float4 hA = hp[0], hB = hp[1];
                    float4 xv = *reinterpret_cast<const float4*>(&xs[1][tt][0]);
                    float  xq = xs[1][tt][4];
                    a01 = DOT4(whA0,hA)+DOT4(whB0,hB) + DOT4(wx0,xv)+wq0*xq;
                    a11 = DOT4(whA1,hA)+DOT4(whB1,hB) + DOT4(wx1,xv)+wq1*xq;
                    a21 = DOT4(whA2,hA)+DOT4(whB2,hB) + DOT4(wx2,xv)+wq2*xq;
                    a31 = DOT4(whA3,hA)+DOT4(whB3,hB) + DOT4(wx3,xv)+wq3*xq;
                }
                a00 = octet_sum(a00) + bi0;  a01 = octet_sum(a01) + bi0;
                a10 = octet_sum(a10) + bi1;  a11 = octet_sum(a11) + bi1;
                a20 = octet_sum(a20) + bi2;  a21 = octet_sum(a21) + bi2;
                a30 = octet_sum(a30) + bi3;  a31 = octet_sum(a31) + bi3;
                float i0 = sigm(a00), f0 = sigm(a10), g0 = tanh_fast(a20), o0 = sigm(a30);
                float i1 = sigm(a01), f1 = sigm(a11), g1 = tanh_fast(a21), o1 = sigm(a31);
                c00 = f0 * c00 + i0 * g0;
                c01 = f1 * c01 + i1 * g1;
                float h0 = o0 * tanh_fast(c00);
                float h1 = o1 * tanh_fast(c01);
                if (s == 0) { buf0[0][tt][u] = h0; buf0[1][tt][u] = h1; }
                __syncthreads();
            }
        }

        // ================= layer 1 =================
        {
            asm volatile("" ::: "memory");
            const float4* pi0 = reinterpret_cast<const float4*>(w_ih1 + (size_t)(0*Hh+u)*Hh + ko);
            const float4* pi1 = reinterpret_cast<const float4*>(w_ih1 + (size_t)(1*Hh+u)*Hh + ko);
            const float4* pi2 = reinterpret_cast<const float4*>(w_ih1 + (size_t)(2*Hh+u)*Hh + ko);
            const float4* pi3 = reinterpret_cast<const float4*>(w_ih1 + (size_t)(3*Hh+u)*Hh + ko);
            float4 wiA0=pi0[0], wiB0=pi0[1];
            float4 wiA1=pi1[0], wiB1=pi1[1];
            float4 wiA2=pi2[0], wiB2=pi2[1];
            float4 wiA3=pi3[0], wiB3=pi3[1];
            const float4* ph0 = reinterpret_cast<const float4*>(w_hh1 + (size_t)(0*Hh+u)*Hh + ko);
            const float4* ph1 = reinterpret_cast<const float4*>(w_hh1 + (size_t)(1*Hh+u)*Hh + ko);
            const float4* ph2 = reinterpret_cast<const float4*>(w_hh1 + (size_t)(2*Hh+u)*Hh + ko);
            const float4* ph3 = reinterpret_cast<const float4*>(w_hh1 + (size_t)(3*Hh+u)*Hh + ko);
            float4 whA0=ph0[0], whB0=ph0[1];
            float4 whA1=ph1[0], whB1=ph1[1];
            float4 whA2=ph2[0], whB2=ph2[1];
            float4 whA3=ph3[0], whB3=ph3[1];
            const float bi0 = b_ih1[0*Hh+u] + b_hh1[0*Hh+u];
            const float bi1 = b_ih1[1*Hh+u] + b_hh1[1*Hh+u];
            const float bi2 = b_ih1[2*Hh+u] + b_hh1[2*Hh+u];
            const float bi3 = b_ih1[3*Hh+u] + b_hh1[3*Hh+u];
            // buf0 chunk complete (final barrier of layer-0 loop)

            #pragma unroll 1
            for (int tt = 0; tt < TC; ++tt) {
                const int tp = (tt == 0) ? (TC - 1) : (tt - 1);
                float a00,a10,a20,a30, a01,a11,a21,a31;
                {
                    const float4* ip = reinterpret_cast<const float4*>(&buf0[0][tt][ko]);
                    float4 iA = ip[0], iB = ip[1];
                    const float4* hp = reinterpret_cast<const float4*>(&buf1[0][tp][ko]);
                    float4 hA = hp[0], hB = hp[1];
                    a00 = (DOT4(wiA0,iA)+DOT4(wiB0,iB)) + (DOT4(whA0,hA)+DOT4(whB0,hB));
                    a10 = (DOT4(wiA1,iA)+DOT4(wiB1,iB)) + (DOT4(whA1,hA)+DOT4(whB1,hB));
                    a20 = (DOT4(wiA2,iA)+DOT4(wiB2,iB)) + (DOT4(whA2,hA)+DOT4(whB2,hB));
                    a30 = (DOT4(wiA3,iA)+DOT4(wiB3,iB)) + (DOT4(whA3,hA)+DOT4(whB3,hB));
                }
                {
                    const float4* ip = reinterpret_cast<const float4*>(&buf0[1][tt][ko]);
                    float4 iA = ip[0], iB = ip[1];
                    const float4* hp = reinterpret_cast<const float4*>(&buf1[1][tp][ko]);
                    float4 hA = hp[0], hB = hp[1];
                    a01 = (DOT4(wiA0,iA)+DOT4(wiB0,iB)) + (DOT4(whA0,hA)+DOT4(whB0,hB));
                    a11 = (DOT4(wiA1,iA)+DOT4(wiB1,iB)) + (DOT4(whA1,hA)+DOT4(whB1,hB));
                    a21 = (DOT4(wiA2,iA)+DOT4(wiB2,iB)) + (DOT4(whA2,hA)+DOT4(whB2,hB));
                    a31 = (DOT4(wiA3,iA)+DOT4(wiB3,iB)) + (DOT4(whA3,hA)+DOT4(whB3,hB));
                }
                a00 = octet_sum(a00) + bi0;  a01 = octet_sum(a01) + bi0;
                a10 = octet_sum(a10) + bi1;  a11 = octet_sum(a11) + bi1;
                a20 = octet_sum(a20) + bi2;  a21 = octet_sum(a21) + bi2;
                a30 = octet_sum(a30) + bi3;  a31 = octet_sum(a31) + bi3;
                float i0 = sigm(a00), f0 = sigm(a10), g0 = tanh_fast(a20), o0 = sigm(a30);
                float i1 = sigm(a01), f1 = sigm(a11), g1 = tanh_fast(a21), o1 = sigm(a31);
                c10 = f0 * c10 + i0 * g0;
                c11 = f1 * c11 + i1 * g1;
                float h0 = o0 * tanh_fast(c10);
                float h1 = o1 * tanh_fast(c11);
                if (s == 0) { buf1[0][tt][u] = h0; buf1[1][tt][u] = h1; }
                __syncthreads();
            }
        }

        // ================= layer 2 =================
        {
            asm volatile("" ::: "memory");
            const float4* pi0 = reinterpret_cast<const float4*>(w_ih2 + (size_t)(0*Hh+u)*Hh + ko);
            const float4* pi1 = reinterpret_cast<const float4*>(w_ih2 + (size_t)(1*Hh+u)*Hh + ko);
            const float4* pi2 = reinterpret_cast<const float4*>(w_ih2 + (size_t)(2*Hh+u)*Hh + ko);
            const float4* pi3 = reinterpret_cast<const float4*>(w_ih2 + (size_t)(3*Hh+u)*Hh + ko);
            float4 wiA0=pi0[0], wiB0=pi0[1];
            float4 wiA1=pi1[0], wiB1=pi1[1];
            float4 wiA2=pi2[0], wiB2=pi2[1];
            float4 wiA3=pi3[0], wiB3=pi3[1];
            const float4* ph0 = reinterpret_cast<const float4*>(w_hh2 + (size_t)(0*Hh+u)*Hh + ko);
            const float4* ph1 = reinterpret_cast<const float4*>(w_hh2 + (size_t)(1*Hh+u)*Hh + ko);
            const float4* ph2 = reinterpret_cast<const float4*>(w_hh2 + (size_t)(2*Hh+u)*Hh + ko);
            const float4* ph3 = reinterpret_cast<const float4*>(w_hh2 + (size_t)(3*Hh+u)*Hh + ko);
            float4 whA0=ph0[0], whB0=ph0[1];
            float4 whA1=ph1[0], whB1=ph1[1];
            float4 whA2=ph2[0], whB2=ph2[1];
            float4 whA3=ph3[0], whB3=ph3[1];
            const float bi0 = b_ih2[0*Hh+u] + b_hh2[0*Hh+u];
            const float bi1 = b_ih2[1*Hh+u] + b_hh2[1*Hh+u];
            const float bi2 = b_ih2[2*Hh+u] + b_hh2[2*Hh+u];
            const float bi3 = b_ih2[3*Hh+u] + b_hh2[3*Hh+u];

            #pragma unroll 1
            for (int tt = 0; tt < TC; ++tt) {
                const int ri = tt & 1, wri = ri ^ 1;   // rolling h2 parity
                float a00,a10,a20,a30, a01,a11,a21,a31;
                {
                    const float4* ip = reinterpret_cast<const float4*>(&buf1[0][tt][ko]);
                    float4 iA = ip[0], iB = ip[1];
                    const float4* hp = reinterpret_cast<const float4*>(&h2b[ri][0][ko]);
                    float4 hA = hp[0], hB = hp[1];
                    a00 = (DOT4(wiA0,iA)+DOT4(wiB0,iB)) + (DOT4(whA0,hA)+DOT4(whB0,hB));
                    a10 = (DOT4(wiA1,iA)+DOT4(wiB1,iB)) + (DOT4(whA1,hA)+DOT4(whB1,hB));
                    a20 = (DOT4(wiA2,iA)+DOT4(wiB2,iB)) + (DOT4(whA2,hA)+DOT4(whB2,hB));
                    a30 = (DOT4(wiA3,iA)+DOT4(wiB3,iB)) + (DOT4(whA3,hA)+DOT4(whB3,hB));
                }
                {
                    const float4* ip = reinterpret_cast<const float4*>(&buf1[1][tt][ko]);
                    float4 iA = ip[0], iB = ip[1];
                    const float4* hp = reinterpret_cast<const float4*>(&h2b[ri][1][ko]);
                    float4 hA = hp[0], hB = hp[1];
                    a01 = (DOT4(wiA0,iA)+DOT4(wiB0,iB)) + (DOT4(whA0,hA)+DOT4(whB0,hB));
                    a11 = (DOT4(wiA1,iA)+DOT4(wiB1,iB)) + (DOT4(whA1,hA)+DOT4(whB1,hB));
                    a21 = (DOT4(wiA2,iA)+DOT4(wiB2,iB)) + (DOT4(whA2,hA)+DOT4(whB2,hB));
                    a31 = (DOT4(wiA3,iA)+DOT4(wiB3,iB)) + (DOT4(whA3,hA)+DOT4(whB3,hB));
                }
                a00 = octet_sum(a00) + bi0;  a01 = octet_sum(a01) + bi0;
                a10 = octet_sum(a10) + bi1;  a11 = octet_sum(a11) + bi1;
                a20 = octet_sum(a20) + bi2;  a21 = octet_sum(a21) + bi2;
                a30 = octet_sum(a30) + bi3;  a31 = octet_sum(a31) + bi3;
                float i0 = sigm(a00), f0 = sigm(a10), g0 = tanh_fast(a20), o0 = sigm(a30);
                float i1 = sigm(a01), f1 = sigm(a11), g1 = tanh_fast(a21), o1 = sigm(a31);
                c20 = f0 * c20 + i0 * g0;
                c21 = f1 * c21 + i1 * g1;
                float h0 = o0 * tanh_fast(c20);
                float h1 = o1 * tanh_fast(c21);
                if (s == 0) { h2b[wri][0][u] = h0; h2b[wri][1][u] = h1; }
                __syncthreads();
            }
        }
    }

    // ---- final FC on h2 at t = T-1 ----
    // last write index = ((TC-1)&1)^1 = 0
    if (tid < TB * Hh) {
        const int cb = tid >> 6, cu = tid & (Hh - 1);
        float p = h2b[0][cb][cu] * w_fc[cu];
        #pragma unroll
        for (int off = 32; off > 0; off >>= 1) p += __shfl_down(p, off, 64);
        if (cu == 0) out[b0 + cb] = p + b_fc[0];
    }
}

extern "C" void kernel_launch(void* const* d_in, const int* in_sizes, int n_in,
                              void* d_out, int out_size, void* d_ws, size_t ws_size,
                              hipStream_t stream) {
    const float* x     = (const float*)d_in[0];
    const float* w_ih0 = (const float*)d_in[1];
    const float* w_hh0 = (const float*)d_in[2];
    const float* b_ih0 = (const float*)d_in[3];
    const float* b_hh0 = (const float*)d_in[4];
    const float* w_ih1 = (const float*)d_in[5];
    const float* w_hh1 = (const float*)d_in[6];
    const float* b_ih1 = (const float*)d_in[7];
    const float* b_hh1 = (const float*)d_in[8];
    const float* w_ih2 = (const float*)d_in[9];
    const float* w_hh2 = (const float*)d_in[10];
    const float* b_ih2 = (const float*)d_in[11];
    const float* b_hh2 = (const float*)d_in[12];
    const float* w_fc  = (const float*)d_in[13];
    const float* b_fc  = (const float*)d_in[14];
    float* out = (float*)d_out;

    lstm3_fused<<<NB, NT, 0, stream>>>(x,
        w_ih0, w_hh0, b_ih0, b_hh0,
        w_ih1, w_hh1, b_ih1, b_hh1,
        w_ih2, w_hh2, b_ih2, b_hh2,
        w_fc, b_fc, out, Tt / TC);
}

// Round 8
// 1746.778 us; speedup vs baseline: 1.2371x; 1.2371x over previous
//
#include <hip/hip_runtime.h>
#include <math.h>

// LSTM: I=5, H=64, L=3, O=1, B=1024, T=256, fp32.
// Round-8: phase split. Only h@w_hh is serial; xg = in@w_ih + b_ih + b_hh is
// precomputed per TC=16 chunk into LDS by a barrier-free GEMM phase (thread =
// gate row, w_ih in 64 regs). Serial phase = r5 quad map (u=tid>>2, s=tid&3,
// 4 gate rows x 16k) with ONLY w_hh resident (64 regs) -> fits the de-facto
// 128-VGPR cap (r5 failed holding both matrices = 128 regs + working set).
// r7 lesson: minimize total instructions, not just spill -- 8-way split
// doubled fixed overhead (reductions/acts) across 512 threads and regressed.
// NT=256, TB=2, 2 blocks/CU, LDS 50 KB. One barrier per serial step.

constexpr int Hh = 64;
constexpr int Tt = 256;   // timesteps
constexpr int In = 5;     // input size
constexpr int TB = 2;     // batch elems per block
constexpr int TC = 16;    // timestep chunk (xg LDS budget)
constexpr int NB = 512;   // blocks (NB*TB = 1024 = B)
constexpr int NT = 256;   // threads per block

__device__ __forceinline__ float sigm(float x) { return 1.0f / (1.0f + __expf(-x)); }
__device__ __forceinline__ float tanh_fast(float x) {
    float ax = fabsf(x);
    float t = __expf(-2.0f * ax);      // in (0,1], no overflow
    float r = (1.0f - t) / (1.0f + t);
    return copysignf(r, x);
}

template<int CTRL>
__device__ __forceinline__ float qp(float v) {
    int r = __builtin_amdgcn_update_dpp(0, __builtin_bit_cast(int, v),
                                        CTRL, 0xF, 0xF, true);
    return __builtin_bit_cast(float, r);
}
__device__ __forceinline__ float quad_sum(float a) {
    a += qp<0xB1>(a);   // xor 1
    a += qp<0x4E>(a);   // xor 2
    return a;
}

#define DOT4(W, H) ((W).x*(H).x + (W).y*(H).y + (W).z*(H).z + (W).w*(H).w)

// ---- serial-phase w_hh loader: 4 gate rows (q*64+u), k in [ko, ko+16) ----
#define LOAD_WHH(WHH) \
    const float4* zq0 = reinterpret_cast<const float4*>((WHH) + (size_t)(0*Hh+u)*Hh + ko); \
    const float4* zq1 = reinterpret_cast<const float4*>((WHH) + (size_t)(1*Hh+u)*Hh + ko); \
    const float4* zq2 = reinterpret_cast<const float4*>((WHH) + (size_t)(2*Hh+u)*Hh + ko); \
    const float4* zq3 = reinterpret_cast<const float4*>((WHH) + (size_t)(3*Hh+u)*Hh + ko); \
    float4 wg00=zq0[0], wg01=zq0[1], wg02=zq0[2], wg03=zq0[3]; \
    float4 wg10=zq1[0], wg11=zq1[1], wg12=zq1[2], wg13=zq1[3]; \
    float4 wg20=zq2[0], wg21=zq2[1], wg22=zq2[2], wg23=zq2[3]; \
    float4 wg30=zq3[0], wg31=zq3[1], wg32=zq3[2], wg33=zq3[3];

// ---- one serial LSTM step (both batch elems); SRCb = &h_prev[b][ko],
//      DSTb = &h_new[b][u]; C0/C1 = c-state registers ----
#define SERIAL_STEP(SRC0, SRC1, DST0, DST1, C0, C1) do { \
    float i0_,f0_,g0_,o0_, i1_,f1_,g1_,o1_; \
    { \
        const float4* hp_ = reinterpret_cast<const float4*>(SRC0); \
        float4 hA_=hp_[0], hB_=hp_[1], hC_=hp_[2], hD_=hp_[3]; \
        float a0_ = DOT4(wg00,hA_)+DOT4(wg01,hB_)+DOT4(wg02,hC_)+DOT4(wg03,hD_); \
        float a1_ = DOT4(wg10,hA_)+DOT4(wg11,hB_)+DOT4(wg12,hC_)+DOT4(wg13,hD_); \
        float a2_ = DOT4(wg20,hA_)+DOT4(wg21,hB_)+DOT4(wg22,hC_)+DOT4(wg23,hD_); \
        float a3_ = DOT4(wg30,hA_)+DOT4(wg31,hB_)+DOT4(wg32,hC_)+DOT4(wg33,hD_); \
        a0_ = quad_sum(a0_) + xgs[0][tt][u]; \
        a1_ = quad_sum(a1_) + xgs[0][tt][Hh+u]; \
        a2_ = quad_sum(a2_) + xgs[0][tt][2*Hh+u]; \
        a3_ = quad_sum(a3_) + xgs[0][tt][3*Hh+u]; \
        i0_=sigm(a0_); f0_=sigm(a1_); g0_=tanh_fast(a2_); o0_=sigm(a3_); \
    } \
    { \
        const float4* hp_ = reinterpret_cast<const float4*>(SRC1); \
        float4 hA_=hp_[0], hB_=hp_[1], hC_=hp_[2], hD_=hp_[3]; \
        float a0_ = DOT4(wg00,hA_)+DOT4(wg01,hB_)+DOT4(wg02,hC_)+DOT4(wg03,hD_); \
        float a1_ = DOT4(wg10,hA_)+DOT4(wg11,hB_)+DOT4(wg12,hC_)+DOT4(wg13,hD_); \
        float a2_ = DOT4(wg20,hA_)+DOT4(wg21,hB_)+DOT4(wg22,hC_)+DOT4(wg23,hD_); \
        float a3_ = DOT4(wg30,hA_)+DOT4(wg31,hB_)+DOT4(wg32,hC_)+DOT4(wg33,hD_); \
        a0_ = quad_sum(a0_) + xgs[1][tt][u]; \
        a1_ = quad_sum(a1_) + xgs[1][tt][Hh+u]; \
        a2_ = quad_sum(a2_) + xgs[1][tt][2*Hh+u]; \
        a3_ = quad_sum(a3_) + xgs[1][tt][3*Hh+u]; \
        i1_=sigm(a0_); f1_=sigm(a1_); g1_=tanh_fast(a2_); o1_=sigm(a3_); \
    } \
    C0 = f0_ * C0 + i0_ * g0_;  float h0_ = o0_ * tanh_fast(C0); \
    C1 = f1_ * C1 + i1_ * g1_;  float h1_ = o1_ * tanh_fast(C1); \
    if (s == 0) { *(DST0) = h0_; *(DST1) = h1_; } \
    __syncthreads(); \
} while (0)

// ---- GEMM phase: xgs[b][t][g] = dot64(w_ih[g], SRC[b][t]) + b_ih[g]+b_hh[g]
#define GEMM64(WIH, BIH, BHH, SRC) do { \
    const float4* wp_ = reinterpret_cast<const float4*>((WIH) + (size_t)g * Hh); \
    float4 wi0_=wp_[0], wi1_=wp_[1], wi2_=wp_[2],  wi3_=wp_[3]; \
    float4 wi4_=wp_[4], wi5_=wp_[5], wi6_=wp_[6],  wi7_=wp_[7]; \
    float4 wi8_=wp_[8], wi9_=wp_[9], wi10_=wp_[10],wi11_=wp_[11]; \
    float4 wi12_=wp_[12],wi13_=wp_[13],wi14_=wp_[14],wi15_=wp_[15]; \
    float bias_ = (BIH)[g] + (BHH)[g]; \
    for (int t2 = 0; t2 < TC; ++t2) { \
        { \
            const float4* ip_ = reinterpret_cast<const float4*>(&(SRC)[0][t2][0]); \
            float a_ = bias_; \
            a_ += DOT4(wi0_,ip_[0]) + DOT4(wi1_,ip_[1]) + DOT4(wi2_,ip_[2]) + DOT4(wi3_,ip_[3]); \
            a_ += DOT4(wi4_,ip_[4]) + DOT4(wi5_,ip_[5]) + DOT4(wi6_,ip_[6]) + DOT4(wi7_,ip_[7]); \
            a_ += DOT4(wi8_,ip_[8]) + DOT4(wi9_,ip_[9]) + DOT4(wi10_,ip_[10]) + DOT4(wi11_,ip_[11]); \
            a_ += DOT4(wi12_,ip_[12]) + DOT4(wi13_,ip_[13]) + DOT4(wi14_,ip_[14]) + DOT4(wi15_,ip_[15]); \
            xgs[0][t2][g] = a_; \
        } \
        { \
            const float4* ip_ = reinterpret_cast<const float4*>(&(SRC)[1][t2][0]); \
            float a_ = bias_; \
            a_ += DOT4(wi0_,ip_[0]) + DOT4(wi1_,ip_[1]) + DOT4(wi2_,ip_[2]) + DOT4(wi3_,ip_[3]); \
            a_ += DOT4(wi4_,ip_[4]) + DOT4(wi5_,ip_[5]) + DOT4(wi6_,ip_[6]) + DOT4(wi7_,ip_[7]); \
            a_ += DOT4(wi8_,ip_[8]) + DOT4(wi9_,ip_[9]) + DOT4(wi10_,ip_[10]) + DOT4(wi11_,ip_[11]); \
            a_ += DOT4(wi12_,ip_[12]) + DOT4(wi13_,ip_[13]) + DOT4(wi14_,ip_[14]) + DOT4(wi15_,ip_[15]); \
            xgs[1][t2][g] = a_; \
        } \
    } \
} while (0)

__global__ __launch_bounds__(NT, 2) void lstm3_fused(
    const float* __restrict__ x,
    const float* __restrict__ w_ih0, const float* __restrict__ w_hh0,
    const float* __restrict__ b_ih0, const float* __restrict__ b_hh0,
    const float* __restrict__ w_ih1, const float* __restrict__ w_hh1,
    const float* __restrict__ b_ih1, const float* __restrict__ b_hh1,
    const float* __restrict__ w_ih2, const float* __restrict__ w_hh2,
    const float* __restrict__ b_ih2, const float* __restrict__ b_hh2,
    const float* __restrict__ w_fc,  const float* __restrict__ b_fc,
    float* __restrict__ out, int nch)
{
    __shared__ alignas(16) float xgs[TB][TC][4 * Hh];  // gate preacts (32 KB)
    __shared__ alignas(16) float buf0[TB][TC][Hh];     // layer0 h chunk (8 KB)
    __shared__ alignas(16) float buf1[TB][TC][Hh];     // layer1 h chunk (8 KB)
    __shared__ alignas(16) float h2b[2][TB][Hh];       // layer2 rolling h (1 KB)
    __shared__ alignas(16) float xs[TB][TC][8];        // staged input (1 KB)

    const int tid = threadIdx.x;
    const int g   = tid;             // GEMM phase: gate row 0..255
    const int u   = tid >> 2;        // serial phase: hidden unit 0..63
    const int s   = tid & 3;         // serial phase: k-quarter
    const int ko  = 16 * s;          // serial k offset
    const int b0  = blockIdx.x * TB;

    float c00 = 0.f, c01 = 0.f;   // c-state, replicated across quad lanes
    float c10 = 0.f, c11 = 0.f;
    float c20 = 0.f, c21 = 0.f;

    for (int i = tid; i < TB * TC * Hh; i += NT) { ((float*)buf0)[i] = 0.f; ((float*)buf1)[i] = 0.f; }
    for (int i = tid; i < 2 * TB * Hh; i += NT) ((float*)h2b)[i] = 0.f;

    #pragma unroll 1
    for (int chunk = 0; chunk < nch; ++chunk) {
        const int t0 = chunk * TC;

        // ---- stage x chunk ----
        for (int i = tid; i < TB * TC * 8; i += NT) {
            int b  = i >> 7;          // TC*8 = 128
            int r  = i & 127;
            int t  = r >> 3;
            int cc = r & 7;
            xs[b][t][cc] = (cc < In)
                ? x[((size_t)(b0 + b) * Tt + (t0 + t)) * In + cc] : 0.f;
        }
        __syncthreads();   // xs staged (+ chunk 0: buffers zeroed)

        // ================= layer 0 =================
        {   // GEMM phase: xg = x @ w_ih0^T + biases (5-wide dot)
            asm volatile("" ::: "memory");
            const float* q_ = w_ih0 + (size_t)g * In;
            float w0_=q_[0], w1_=q_[1], w2_=q_[2], w3_=q_[3], w4_=q_[4];
            float bias_ = b_ih0[g] + b_hh0[g];
            for (int t2 = 0; t2 < TC; ++t2) {
                xgs[0][t2][g] = bias_ + w0_*xs[0][t2][0] + w1_*xs[0][t2][1]
                              + w2_*xs[0][t2][2] + w3_*xs[0][t2][3] + w4_*xs[0][t2][4];
                xgs[1][t2][g] = bias_ + w0_*xs[1][t2][0] + w1_*xs[1][t2][1]
                              + w2_*xs[1][t2][2] + w3_*xs[1][t2][3] + w4_*xs[1][t2][4];
            }
        }
        __syncthreads();
        {   // serial phase
            asm volatile("" ::: "memory");
            LOAD_WHH(w_hh0);
            #pragma unroll 1
            for (int tt = 0; tt < TC; ++tt) {
                const int tp = (tt == 0) ? (TC - 1) : (tt - 1);
                SERIAL_STEP(&buf0[0][tp][ko], &buf0[1][tp][ko],
                            &buf0[0][tt][u],  &buf0[1][tt][u], c00, c01);
            }
        }

        // ================= layer 1 =================
        {
            asm volatile("" ::: "memory");
            GEMM64(w_ih1, b_ih1, b_hh1, buf0);
        }
        __syncthreads();
        {
            asm volatile("" ::: "memory");
            LOAD_WHH(w_hh1);
            #pragma unroll 1
            for (int tt = 0; tt < TC; ++tt) {
                const int tp = (tt == 0) ? (TC - 1) : (tt - 1);
                SERIAL_STEP(&buf1[0][tp][ko], &buf1[1][tp][ko],
                            &buf1[0][tt][u],  &buf1[1][tt][u], c10, c11);
            }
        }

        // ================= layer 2 =================
        {
            asm volatile("" ::: "memory");
            GEMM64(w_ih2, b_ih2, b_hh2, buf1);
        }
        __syncthreads();
        {
            asm volatile("" ::: "memory");
            LOAD_WHH(w_hh2);
            #pragma unroll 1
            for (int tt = 0; tt < TC; ++tt) {
                const int ri = tt & 1, wri = ri ^ 1;   // rolling parity
                SERIAL_STEP(&h2b[ri][0][ko], &h2b[ri][1][ko],
                            &h2b[wri][0][u], &h2b[wri][1][u], c20, c21);
            }
        }
    }

    // ---- final FC on h2 at t = T-1 (last write parity = ((TC-1)&1)^1 = 0) ----
    if (tid < TB * Hh) {
        const int cb = tid >> 6, cu = tid & (Hh - 1);
        float p = h2b[0][cb][cu] * w_fc[cu];
        #pragma unroll
        for (int off = 32; off > 0; off >>= 1) p += __shfl_down(p, off, 64);
        if (cu == 0) out[b0 + cb] = p + b_fc[0];
    }
}

extern "C" void kernel_launch(void* const* d_in, const int* in_sizes, int n_in,
                              void* d_out, int out_size, void* d_ws, size_t ws_size,
                              hipStream_t stream) {
    const float* x     = (const float*)d_in[0];
    const float* w_ih0 = (const float*)d_in[1];
    const float* w_hh0 = (const float*)d_in[2];
    const float* b_ih0 = (const float*)d_in[3];
    const float* b_hh0 = (const float*)d_in[4];
    const float* w_ih1 = (const float*)d_in[5];
    const float* w_hh1 = (const float*)d_in[6];
    const float* b_ih1 = (const float*)d_in[7];
    const float* b_hh1 = (const float*)d_in[8];
    const float* w_ih2 = (const float*)d_in[9];
    const float* w_hh2 = (const float*)d_in[10];
    const float* b_ih2 = (const float*)d_in[11];
    const float* b_hh2 = (const float*)d_in[12];
    const float* w_fc  = (const float*)d_in[13];
    const float* b_fc  = (const float*)d_in[14];
    float* out = (float*)d_out;

    lstm3_fused<<<NB, NT, 0, stream>>>(x,
        w_ih0, w_hh0, b_ih0, b_hh0,
        w_ih1, w_hh1, b_ih1, b_hh1,
        w_ih2, w_hh2, b_ih2, b_hh2,
        w_fc, b_fc, out, Tt / TC);
}